// Round 19
// baseline (147.037 us; speedup 1.0000x reference)
//
#include <hip/hip_runtime.h>
#include <cstdint>
#include <cstddef>

#define B_ 4
#define T_ 2048
#define C_ 768
#define H_ 16
#define D_ 48
#define M_ (B_*T_)      // 8192
#define N3_ (3*C_)      // 2304

typedef unsigned short u16;
typedef __attribute__((ext_vector_type(8))) short bf16x8;
typedef __attribute__((ext_vector_type(4))) float f32x4;
typedef __attribute__((ext_vector_type(4))) unsigned int u32x4;
typedef __attribute__((ext_vector_type(4))) unsigned short u16x4;

typedef const __attribute__((address_space(1))) unsigned int* gptr_t;
typedef __attribute__((address_space(3))) unsigned int* lptr_t;

__device__ __forceinline__ u16 f2b(float f){
  union { float f; unsigned u; } x; x.f = f;
  unsigned u = x.u;
  return (u16)((u + 0x7FFFu + ((u >> 16) & 1u)) >> 16);
}

// v_cvt_pk_bf16_f32: packs {bf16(lo), bf16(hi)} into one u32 (RNE).
__device__ __forceinline__ unsigned cvtpk(float lo, float hi){
  unsigned r;
  asm("v_cvt_pk_bf16_f32 %0, %1, %2" : "=v"(r) : "v"(lo), "v"(hi));
  return r;
}

// Swizzled LDS fragment load (128B-pitch tiles, V + GEMM).
// Physical byte = row*128 + (col_byte ^ ((row&7)<<4)).
__device__ __forceinline__ bf16x8 ld_frag(const u16* lds, int row, int kbyte){
  const char* p = (const char*)lds + (row << 7) + (kbyte ^ ((row & 7) << 4));
  return *(const bf16x8*)p;
}

// Unswizzled 96B-pitch K fragment load: rbase = ls*96 + hi*16 (runtime),
// off = nf*1536 + kk*64 (compile-time immediate). Banks are uniformly
// distributed ((24*ls+4*hi) mod 32 covers all starts evenly) -> no swizzle.
__device__ __forceinline__ bf16x8 ld_k(const u16* kb, int rbase, int off){
  return *(const bf16x8*)((const char*)kb + rbase + off);
}

// ---------------- fp32 -> bf16 convert (vectorized x4) ----------------
__global__ void k_cvt(const float* __restrict__ in, u16* __restrict__ out, int n4){
  int i = blockIdx.x * blockDim.x + threadIdx.x;
  if (i >= n4) return;
  f32x4 v = *(const f32x4*)(in + 4*(size_t)i);
  u16x4 o;
  o.x = f2b(v.x); o.y = f2b(v.y); o.z = f2b(v.z); o.w = f2b(v.w);
  *(u16x4*)(out + 4*(size_t)i) = o;
}

// ------ fp32 [R][Cn] -> bf16 transposed [Cn][R]; rows < scaleRows get *scl ------
__global__ void k_tpose(const float* __restrict__ in, u16* __restrict__ out, int R, int Cn,
                        int scaleRows, float scl){
  __shared__ float tile[32][33];
  int tx = threadIdx.x & 31, ty = threadIdx.x >> 5;  // ty 0..7
  int c  = blockIdx.x * 32 + tx;
  int rb = blockIdx.y * 32;
  #pragma unroll
  for (int r0 = 0; r0 < 32; r0 += 8)
    tile[ty + r0][tx] = in[(size_t)(rb + ty + r0) * Cn + c];
  __syncthreads();
  int oc = rb + tx;
  int cb = blockIdx.x * 32;
  #pragma unroll
  for (int r0 = 0; r0 < 32; r0 += 8){
    float v = tile[tx][ty + r0];
    if (cb + ty + r0 < scaleRows) v *= scl;
    out[(size_t)(cb + ty + r0) * R + oc] = f2b(v);
  }
}

// ---------------- bf16 GEMM: C[m][n] = sum_k A[m][k]*Bt[n][k] ----------------
// GEMM1 only (vtOut != nullptr): blocks with n0 >= 2C write their tile DIRECTLY
// into vt[b*768 + (col-2C)][t] via 8B u16x4 stores (acc[..][r] r=0..3 are 4
// consecutive t's of one vt row) and skip the qkv store -- the V region of qkv
// is never materialized and the k_vt pass is eliminated.
template<bool OUT_BF16, bool ADD_BIAS>
__launch_bounds__(256)
__global__ void k_gemm(const u16* __restrict__ A, const u16* __restrict__ Bt,
                       void* __restrict__ Cout, const float* __restrict__ bias,
                       int Ndim, int Kdim, u16* __restrict__ vtOut){
  __shared__ u16 lA[128*64];
  __shared__ u16 lB[128*64];
  const int tid = threadIdx.x, lane = tid & 63, w = tid >> 6;
  const int m0 = blockIdx.x * 128, n0 = blockIdx.y * 128;
  const int wr = (w >> 1) * 64, wc = (w & 1) * 64;
  const f32x4 fzero = {0.f, 0.f, 0.f, 0.f};
  f32x4 acc[4][4];
  #pragma unroll
  for (int i = 0; i < 4; ++i)
    #pragma unroll
    for (int j = 0; j < 4; ++j) acc[i][j] = fzero;

  for (int k0 = 0; k0 < Kdim; k0 += 64){
    __syncthreads();
    #pragma unroll
    for (int it = 0; it < 4; ++it){
      int c = tid + it * 256;              // 0..1023
      int row  = c >> 3;
      int cb   = (c & 7) << 4;
      int pcol = cb ^ ((row & 7) << 4);
      const char* ga = (const char*)(A  + (size_t)(m0 + row) * Kdim + k0) + pcol;
      const char* gb = (const char*)(Bt + (size_t)(n0 + row) * Kdim + k0) + pcol;
      __builtin_amdgcn_global_load_lds((gptr_t)ga, (lptr_t)((char*)lA + (c << 4)), 16, 0, 0);
      __builtin_amdgcn_global_load_lds((gptr_t)gb, (lptr_t)((char*)lB + (c << 4)), 16, 0, 0);
    }
    __syncthreads();
    #pragma unroll
    for (int kk = 0; kk < 2; ++kk){
      int kbyte = (kk << 6) + ((lane >> 4) << 4);
      bf16x8 af[4], bfv[4];
      #pragma unroll
      for (int i = 0; i < 4; ++i){
        af[i]  = ld_frag(lA, wr + i*16 + (lane & 15), kbyte);
        bfv[i] = ld_frag(lB, wc + i*16 + (lane & 15), kbyte);
      }
      #pragma unroll
      for (int i = 0; i < 4; ++i)
        #pragma unroll
        for (int j = 0; j < 4; ++j)
          acc[i][j] = __builtin_amdgcn_mfma_f32_16x16x32_bf16(af[i], bfv[j], acc[i][j], 0, 0, 0);
    }
  }
  const int ls = lane & 15, hi = lane >> 4;
  if (vtOut != nullptr && n0 >= 2*C_){
    // V-block: transposed store straight into vt (8B per (i,j))
    const int b2 = m0 >> 11;
    #pragma unroll
    for (int i = 0; i < 4; ++i){
      int t0 = m0 + wr + i*16 + hi*4;     // 4 consecutive t via r
      #pragma unroll
      for (int j = 0; j < 4; ++j){
        int cv = (n0 - 2*C_) + wc + j*16 + ls;
        u16x4 ov;
        #pragma unroll
        for (int r = 0; r < 4; ++r) ov[r] = f2b(acc[i][j][r]);
        *(u16x4*)(vtOut + ((size_t)b2*768 + cv) * T_ + (t0 & 2047)) = ov;
      }
    }
    return;
  }
  #pragma unroll
  for (int i = 0; i < 4; ++i){
    int rbase = m0 + wr + i*16 + (hi << 2);
    #pragma unroll
    for (int j = 0; j < 4; ++j){
      int col = n0 + wc + j*16 + ls;
      float bv = ADD_BIAS ? bias[col] : 0.f;
      #pragma unroll
      for (int r = 0; r < 4; ++r){
        float v = acc[i][j][r] + bv;
        if (OUT_BF16) ((u16*)Cout)[(size_t)(rbase + r) * Ndim + col] = f2b(v);
        else          ((float*)Cout)[(size_t)(rbase + r) * Ndim + col] = v;
      }
    }
  }
}

// ---------------- causal flash attention, anti-diagonal pairs + LPT order ----------------
// grid: 1024 blocks; block = 256 (4 waves). Block owns q-tiles (qbA=p, qbB=31-p).
// LPT dispatch: longest pairs first within each XCD's stream; each XCD owns 8
// complete (b,h) K/V working sets. Swapped-operand MFMA, register-P, fixed-max
// softmax, 96B-pitch K, 48KB LDS (r18 verbatim).
__launch_bounds__(256)
__global__ void k_attn(const u16* __restrict__ qkv, const u16* __restrict__ vt,
                       u16* __restrict__ ao){
  __shared__ u16 lKV[2][2][6144];   // [buf][strip]: K 6144B (64 rows x 96B) + V 6144B

  const int wg = ((blockIdx.x & 7) << 7) + (blockIdx.x >> 3);   // XCD-major, 0..1023
  const int q  = wg & 127;                  // position within this XCD's stream
  const int pairI = q >> 3;                 // 0..15: longest pairs dispatched first
  const int bh = ((wg >> 7) << 3) + (q & 7);  // 8 bh per XCD (L2 locality)
  const int qbA = pairI, qbB = 31 - pairI;
  const int b = bh >> 4, h = bh & 15;
  const int tid = threadIdx.x, lane = tid & 63, w = tid >> 6;
  const int ls = lane & 15, hi = lane >> 4;
  const int krb = ls * 96 + hi * 16;     // K fragment per-lane byte base
  const f32x4 fzero = {0.f, 0.f, 0.f, 0.f};
  const bf16x8 bzero = {0, 0, 0, 0, 0, 0, 0, 0};

  // ---- Q fragments (B-operand layout; Q pre-scaled via W_attn fold) ----
  bf16x8 aqA[2], aqB[2];
  {
    const u16* qpA = qkv + (size_t)(b*T_ + qbA*64 + w*16 + ls) * N3_ + h*D_ + hi*8;
    aqA[0] = *(const bf16x8*)qpA;
    aqA[1] = (hi < 2) ? *(const bf16x8*)(qpA + 32) : bzero;
    const u16* qpB = qkv + (size_t)(b*T_ + qbB*64 + w*16 + ls) * N3_ + h*D_ + hi*8;
    aqB[0] = *(const bf16x8*)qpB;
    aqB[1] = (hi < 2) ? *(const bf16x8*)(qpB + 32) : bzero;
  }

  // ---- staging addresses ----
  const char* kg0; const char* kg1; const char* vg;
  {
    int c0 = tid,       r0 = c0 / 6, i0 = (c0 % 6) << 4;
    int c1 = tid + 256, r1 = c1 / 6, i1 = (c1 % 6) << 4;
    kg0 = (const char*)(qkv + (size_t)(b*T_ + r0) * N3_ + C_ + h*D_) + i0;
    kg1 = (const char*)(qkv + (size_t)(b*T_ + r1) * N3_ + C_ + h*D_) + i1;
    int d0  = tid >> 5;                 // 0..7
    int pb4 = (tid << 2) & 127;         // physical byte in 128B row
    int lb  = pb4 ^ (d0 << 4);          // logical byte
    int k   = lb >> 1;                  // even logical column
    int sk  = (k & 0x23) | ((k & 4) << 2) | ((k & 0x18) >> 1);  // sigma(k)
    vg = (const char*)(vt + (size_t)(bh*D_ + d0) * T_) + (sk << 1);
  }
  const size_t kstep = (size_t)64 * N3_ * 2;   // 64 K-rows per strip

  // stage ONE 64-key strip s into [buf][sl]
  auto STAGE1 = [&](int s, int buf, int sl){
    const size_t ko = (size_t)s * kstep;
    const int vo = s * 128;
    char* base = (char*)&lKV[buf][sl][0];
    __builtin_amdgcn_global_load_lds((gptr_t)(kg0 + ko), (lptr_t)(base + (tid << 4)), 16, 0, 0);
    if (tid < 128)
      __builtin_amdgcn_global_load_lds((gptr_t)(kg1 + ko), (lptr_t)(base + ((tid + 256) << 4)), 16, 0, 0);
    char* vd = base + 6144;
    #pragma unroll
    for (int it = 0; it < 6; ++it)
      __builtin_amdgcn_global_load_lds((gptr_t)(vg + vo + it * (8 * T_ * 2)),
          (lptr_t)(vd + ((tid + it*256) << 2)), 4, 0, 0);
  };

  float lsumA = 0.f, lsumB = 0.f;
  f32x4 oaccA[3], oaccB[3];
  #pragma unroll
  for (int nf = 0; nf < 3; ++nf){ oaccA[nf] = fzero; oaccB[nf] = fzero; }

  int cur = 0;

  // fixed-max softmax on S^T regs: s[nf][r] = S[key=16nf+4hi+r][q=ls].
  auto softmax = [&](f32x4 (&s)[4], float &lsum,
                     bf16x8 &pb0, bf16x8 &pb1, bool diag, int krow0, int qt){
    if (diag){
      int qg = qt + w*16 + ls;
      #pragma unroll
      for (int nf = 0; nf < 4; ++nf)
        #pragma unroll
        for (int r = 0; r < 4; ++r){
          int kg2 = krow0 + nf*16 + hi*4 + r;
          s[nf][r] = (kg2 <= qg) ? s[nf][r] : -1e30f;
        }
    }
    float p[4][4];
    #pragma unroll
    for (int nf = 0; nf < 4; ++nf)
      #pragma unroll
      for (int r = 0; r < 4; ++r){
        float e = __builtin_amdgcn_exp2f(fminf(s[nf][r], 60.f));
        p[nf][r] = e;
        lsum += e;
      }
    union { u32x4 u; bf16x8 b; } w0, w1;
    w0.u.x = cvtpk(p[0][0], p[0][1]); w0.u.y = cvtpk(p[0][2], p[0][3]);
    w0.u.z = cvtpk(p[1][0], p[1][1]); w0.u.w = cvtpk(p[1][2], p[1][3]);
    w1.u.x = cvtpk(p[2][0], p[2][1]); w1.u.y = cvtpk(p[2][2], p[2][3]);
    w1.u.z = cvtpk(p[3][0], p[3][1]); w1.u.w = cvtpk(p[3][2], p[3][3]);
    pb0 = w0.b; pb1 = w1.b;
  };

  // process one 64-key strip (global strip index ks, LDS slot sl)
  auto process = [&](int ks, int sl){
    const bool actA = (ks <= qbA);
    const u16* Kb = &lKV[cur][sl][0];
    const u16* Vb = Kb + 3072;

    f32x4 stA[4], stB[4];
    #pragma unroll
    for (int nf = 0; nf < 4; ++nf){ stA[nf] = fzero; stB[nf] = fzero; }
    #pragma unroll
    for (int kk = 0; kk < 2; ++kk){
      #pragma unroll
      for (int nf = 0; nf < 4; ++nf){
        bf16x8 bk = ld_k(Kb, krb, nf*1536 + (kk << 6));
        stB[nf] = __builtin_amdgcn_mfma_f32_16x16x32_bf16(bk, aqB[kk], stB[nf], 0, 0, 0);
        if (actA)
          stA[nf] = __builtin_amdgcn_mfma_f32_16x16x32_bf16(bk, aqA[kk], stA[nf], 0, 0, 0);
      }
    }

    bf16x8 pbA0, pbA1, pbB0, pbB1;
    if (actA) softmax(stA, lsumA, pbA0, pbA1, ks == qbA, ks*64, qbA*64);
    softmax(stB, lsumB, pbB0, pbB1, ks == qbB, ks*64, qbB*64);

    #pragma unroll
    for (int kk = 0; kk < 2; ++kk){
      int kbyte = (kk << 6) + (hi << 4);
      #pragma unroll
      for (int nf = 0; nf < 3; ++nf){
        bf16x8 bv = ld_frag(Vb, nf*16 + ls, kbyte);
        oaccB[nf] = __builtin_amdgcn_mfma_f32_16x16x32_bf16(
            bv, kk ? pbB1 : pbB0, oaccB[nf], 0, 0, 0);
        if (actA)
          oaccA[nf] = __builtin_amdgcn_mfma_f32_16x16x32_bf16(
              bv, kk ? pbA1 : pbA0, oaccA[nf], 0, 0, 0);
      }
    }
  };

  const int kb2max = qbB >> 1;
  STAGE1(0, 0, 0);
  if (qbB >= 1) STAGE1(1, 0, 1);
  __syncthreads();

  for (int kb2 = 0; kb2 <= kb2max; ++kb2){
    if (kb2 < kb2max){
      STAGE1(2*kb2 + 2, cur ^ 1, 0);
      if (2*kb2 + 3 <= qbB) STAGE1(2*kb2 + 3, cur ^ 1, 1);
    }

    process(2*kb2, 0);
    if (2*kb2 + 1 <= qbB) process(2*kb2 + 1, 1);

    if (kb2 < kb2max){
      __syncthreads();
      cur ^= 1;
    }
  }

  // ---- epilogue: finish lsum across hi-groups, normalize, store O^T ----
  float lA = lsumA; lA += __shfl_xor(lA, 16); lA += __shfl_xor(lA, 32);
  float lB = lsumB; lB += __shfl_xor(lB, 16); lB += __shfl_xor(lB, 32);
  float invA = 1.f / lA, invB = 1.f / lB;
  int tA = qbA*64 + w*16 + ls, tB = qbB*64 + w*16 + ls;
  #pragma unroll
  for (int nf = 0; nf < 3; ++nf){
    u16x4 oA, oB;
    #pragma unroll
    for (int r = 0; r < 4; ++r){
      oA[r] = f2b(oaccA[nf][r] * invA);   // O[q=ls][d = nf*16 + 4hi + r]
      oB[r] = f2b(oaccB[nf][r] * invB);
    }
    int col = h*D_ + nf*16 + hi*4;
    *(u16x4*)(ao + (size_t)(b*T_ + tA) * C_ + col) = oA;
    *(u16x4*)(ao + (size_t)(b*T_ + tB) * C_ + col) = oB;
  }
}

extern "C" void kernel_launch(void* const* d_in, const int* in_sizes, int n_in,
                              void* d_out, int out_size, void* d_ws, size_t ws_size,
                              hipStream_t stream){
  if (n_in < 4) return;
  const float* x      = (const float*)d_in[0];
  const float* W_attn = (const float*)d_in[1];
  const float* W_proj = (const float*)d_in[2];
  const float* b_proj = (const float*)d_in[3];

  char* ws = (char*)d_ws;
  size_t off = 0;
  auto alloc = [&](size_t bytes)->void*{
    void* p = ws + off; off += (bytes + 255) & ~(size_t)255; return p;
  };
  u16* xb   = (u16*)alloc((size_t)M_ * C_  * 2);
  u16* wabT = (u16*)alloc((size_t)N3_ * C_ * 2);
  u16* wpbT = (u16*)alloc((size_t)C_ * C_  * 2);
  u16* qkv  = (u16*)alloc((size_t)M_ * N3_ * 2);
  u16* vt   = (u16*)alloc((size_t)B_ * H_ * D_ * T_ * 2);
  u16* ao   = (u16*)alloc((size_t)M_ * C_  * 2);
  if (off > ws_size) return;  // workspace too small — bail cleanly

  const float scale2 = 0.20823527f;    // 48^-0.5 * log2(e), folded into W_attn Q-cols

  k_cvt<<<dim3((M_*C_/4 + 255)/256), dim3(256), 0, stream>>>(x, xb, M_*C_/4);
  k_tpose<<<dim3(N3_/32, C_/32), dim3(256), 0, stream>>>(W_attn, wabT, C_, N3_, C_, scale2);
  k_tpose<<<dim3(C_/32,  C_/32), dim3(256), 0, stream>>>(W_proj, wpbT, C_, C_, 0, 1.f);
  k_gemm<true,false><<<dim3(M_/128, N3_/128), dim3(256), 0, stream>>>(
      xb, wabT, (void*)qkv, (const float*)nullptr, N3_, C_, vt);
  k_attn<<<dim3(1024), dim3(256), 0, stream>>>(qkv, vt, ao);
  k_gemm<false,true><<<dim3(M_/128, C_/128), dim3(256), 0, stream>>>(
      ao, wpbT, d_out, b_proj, C_, C_, (u16*)nullptr);
}

// Round 22
// 136.894 us; speedup vs baseline: 1.0741x; 1.0741x over previous
//
#include <hip/hip_runtime.h>
#include <cstdint>
#include <cstddef>

#define B_ 4
#define T_ 2048
#define C_ 768
#define H_ 16
#define D_ 48
#define M_ (B_*T_)      // 8192
#define N3_ (3*C_)      // 2304

typedef unsigned short u16;
typedef __attribute__((ext_vector_type(8))) short bf16x8;
typedef __attribute__((ext_vector_type(4))) float f32x4;
typedef __attribute__((ext_vector_type(4))) unsigned int u32x4;
typedef __attribute__((ext_vector_type(4))) unsigned short u16x4;

typedef const __attribute__((address_space(1))) unsigned int* gptr_t;
typedef __attribute__((address_space(3))) unsigned int* lptr_t;

__device__ __forceinline__ u16 f2b(float f){
  union { float f; unsigned u; } x; x.f = f;
  unsigned u = x.u;
  return (u16)((u + 0x7FFFu + ((u >> 16) & 1u)) >> 16);
}

// v_cvt_pk_bf16_f32: packs {bf16(lo), bf16(hi)} into one u32 (RNE).
__device__ __forceinline__ unsigned cvtpk(float lo, float hi){
  unsigned r;
  asm("v_cvt_pk_bf16_f32 %0, %1, %2" : "=v"(r) : "v"(lo), "v"(hi));
  return r;
}

// Swizzled LDS fragment load (128B-pitch tiles, V + GEMM).
// Physical byte = row*128 + (col_byte ^ ((row&7)<<4)).
__device__ __forceinline__ bf16x8 ld_frag(const u16* lds, int row, int kbyte){
  const char* p = (const char*)lds + (row << 7) + (kbyte ^ ((row & 7) << 4));
  return *(const bf16x8*)p;
}

// Unswizzled 96B-pitch K fragment load: rbase = ls*96 + hi*16 (runtime),
// off = nf*1536 + kk*64 (compile-time immediate). Banks are uniformly
// distributed ((24*ls+4*hi) mod 32 covers all starts evenly) -> no swizzle.
__device__ __forceinline__ bf16x8 ld_k(const u16* kb, int rbase, int off){
  return *(const bf16x8*)((const char*)kb + rbase + off);
}

// ---------------- fp32 -> bf16 convert (vectorized x4) ----------------
__global__ void k_cvt(const float* __restrict__ in, u16* __restrict__ out, int n4){
  int i = blockIdx.x * blockDim.x + threadIdx.x;
  if (i >= n4) return;
  f32x4 v = *(const f32x4*)(in + 4*(size_t)i);
  u16x4 o;
  o.x = f2b(v.x); o.y = f2b(v.y); o.z = f2b(v.z); o.w = f2b(v.w);
  *(u16x4*)(out + 4*(size_t)i) = o;
}

// ------ fp32 [R][Cn] -> bf16 transposed [Cn][R]; rows < scaleRows get *scl ------
__global__ void k_tpose(const float* __restrict__ in, u16* __restrict__ out, int R, int Cn,
                        int scaleRows, float scl){
  __shared__ float tile[32][33];
  int tx = threadIdx.x & 31, ty = threadIdx.x >> 5;  // ty 0..7
  int c  = blockIdx.x * 32 + tx;
  int rb = blockIdx.y * 32;
  #pragma unroll
  for (int r0 = 0; r0 < 32; r0 += 8)
    tile[ty + r0][tx] = in[(size_t)(rb + ty + r0) * Cn + c];
  __syncthreads();
  int oc = rb + tx;
  int cb = blockIdx.x * 32;
  #pragma unroll
  for (int r0 = 0; r0 < 32; r0 += 8){
    float v = tile[tx][ty + r0];
    if (cb + ty + r0 < scaleRows) v *= scl;
    out[(size_t)(cb + ty + r0) * R + oc] = f2b(v);
  }
}

// ---------------- bf16 GEMM (128x128 tile): C[m][n] = sum_k A[m][k]*Bt[n][k] ----------------
template<bool OUT_BF16, bool ADD_BIAS>
__launch_bounds__(256)
__global__ void k_gemm(const u16* __restrict__ A, const u16* __restrict__ Bt,
                       void* __restrict__ Cout, const float* __restrict__ bias,
                       int Ndim, int Kdim){
  __shared__ u16 lA[128*64];
  __shared__ u16 lB[128*64];
  const int tid = threadIdx.x, lane = tid & 63, w = tid >> 6;
  const int m0 = blockIdx.x * 128, n0 = blockIdx.y * 128;
  const int wr = (w >> 1) * 64, wc = (w & 1) * 64;
  const f32x4 fzero = {0.f, 0.f, 0.f, 0.f};
  f32x4 acc[4][4];
  #pragma unroll
  for (int i = 0; i < 4; ++i)
    #pragma unroll
    for (int j = 0; j < 4; ++j) acc[i][j] = fzero;

  for (int k0 = 0; k0 < Kdim; k0 += 64){
    __syncthreads();
    #pragma unroll
    for (int it = 0; it < 4; ++it){
      int c = tid + it * 256;              // 0..1023
      int row  = c >> 3;
      int cb   = (c & 7) << 4;
      int pcol = cb ^ ((row & 7) << 4);
      const char* ga = (const char*)(A  + (size_t)(m0 + row) * Kdim + k0) + pcol;
      const char* gb = (const char*)(Bt + (size_t)(n0 + row) * Kdim + k0) + pcol;
      __builtin_amdgcn_global_load_lds((gptr_t)ga, (lptr_t)((char*)lA + (c << 4)), 16, 0, 0);
      __builtin_amdgcn_global_load_lds((gptr_t)gb, (lptr_t)((char*)lB + (c << 4)), 16, 0, 0);
    }
    __syncthreads();
    #pragma unroll
    for (int kk = 0; kk < 2; ++kk){
      int kbyte = (kk << 6) + ((lane >> 4) << 4);
      bf16x8 af[4], bfv[4];
      #pragma unroll
      for (int i = 0; i < 4; ++i){
        af[i]  = ld_frag(lA, wr + i*16 + (lane & 15), kbyte);
        bfv[i] = ld_frag(lB, wc + i*16 + (lane & 15), kbyte);
      }
      #pragma unroll
      for (int i = 0; i < 4; ++i)
        #pragma unroll
        for (int j = 0; j < 4; ++j)
          acc[i][j] = __builtin_amdgcn_mfma_f32_16x16x32_bf16(af[i], bfv[j], acc[i][j], 0, 0, 0);
    }
  }
  #pragma unroll
  for (int i = 0; i < 4; ++i){
    int rbase = m0 + wr + i*16 + ((lane >> 4) << 2);
    #pragma unroll
    for (int j = 0; j < 4; ++j){
      int col = n0 + wc + j*16 + (lane & 15);
      float bv = ADD_BIAS ? bias[col] : 0.f;
      #pragma unroll
      for (int r = 0; r < 4; ++r){
        float v = acc[i][j][r] + bv;
        if (OUT_BF16) ((u16*)Cout)[(size_t)(rbase + r) * Ndim + col] = f2b(v);
        else          ((float*)Cout)[(size_t)(rbase + r) * Ndim + col] = v;
      }
    }
  }
}

// ---------------- bf16 GEMM, 64x128 tile (GEMM2 load balance) ----------------
// M-tile 64 -> grid (M/64, N/128) = 768 blocks = 3/CU even (vs 384 = 1.5/CU).
// 4 waves side-by-side: wave w covers cols [wc, wc+32), all 64 rows. 24KB LDS.
__launch_bounds__(256)
__global__ void k_gemm2(const u16* __restrict__ A, const u16* __restrict__ Bt,
                        float* __restrict__ Cout, const float* __restrict__ bias,
                        int Ndim, int Kdim){
  __shared__ u16 lA[64*64];     // 64 rows x 128B
  __shared__ u16 lB[128*64];    // 128 rows x 128B
  const int tid = threadIdx.x, lane = tid & 63, w = tid >> 6;
  const int m0 = blockIdx.x * 64, n0 = blockIdx.y * 128;
  const int wc = w * 32;
  const int ls = lane & 15, hi = lane >> 4;
  const f32x4 fzero = {0.f, 0.f, 0.f, 0.f};
  f32x4 acc[4][2];
  #pragma unroll
  for (int i = 0; i < 4; ++i){ acc[i][0] = fzero; acc[i][1] = fzero; }

  for (int k0 = 0; k0 < Kdim; k0 += 64){
    __syncthreads();
    // A: 512 chunks (2/thread)
    #pragma unroll
    for (int it = 0; it < 2; ++it){
      int c = tid + it * 256;
      int row = c >> 3, cb = (c & 7) << 4;
      int pcol = cb ^ ((row & 7) << 4);
      const char* ga = (const char*)(A + (size_t)(m0 + row) * Kdim + k0) + pcol;
      __builtin_amdgcn_global_load_lds((gptr_t)ga, (lptr_t)((char*)lA + (c << 4)), 16, 0, 0);
    }
    // B: 1024 chunks (4/thread)
    #pragma unroll
    for (int it = 0; it < 4; ++it){
      int c = tid + it * 256;
      int row = c >> 3, cb = (c & 7) << 4;
      int pcol = cb ^ ((row & 7) << 4);
      const char* gb = (const char*)(Bt + (size_t)(n0 + row) * Kdim + k0) + pcol;
      __builtin_amdgcn_global_load_lds((gptr_t)gb, (lptr_t)((char*)lB + (c << 4)), 16, 0, 0);
    }
    __syncthreads();
    #pragma unroll
    for (int kk = 0; kk < 2; ++kk){
      int kbyte = (kk << 6) + (hi << 4);
      bf16x8 af[4], bfv[2];
      #pragma unroll
      for (int i = 0; i < 4; ++i) af[i] = ld_frag(lA, i*16 + ls, kbyte);
      #pragma unroll
      for (int j = 0; j < 2; ++j) bfv[j] = ld_frag(lB, wc + j*16 + ls, kbyte);
      #pragma unroll
      for (int i = 0; i < 4; ++i)
        #pragma unroll
        for (int j = 0; j < 2; ++j)
          acc[i][j] = __builtin_amdgcn_mfma_f32_16x16x32_bf16(af[i], bfv[j], acc[i][j], 0, 0, 0);
    }
  }
  #pragma unroll
  for (int i = 0; i < 4; ++i){
    int rbase = m0 + i*16 + (hi << 2);
    #pragma unroll
    for (int j = 0; j < 2; ++j){
      int col = n0 + wc + j*16 + ls;
      float bv = bias[col];
      #pragma unroll
      for (int r = 0; r < 4; ++r)
        Cout[(size_t)(rbase + r) * Ndim + col] = acc[i][j][r] + bv;
    }
  }
}

// ---------------- V transpose: vt[bh][d][t] from qkv ----------------
__global__ void k_vt(const u16* __restrict__ qkv, u16* __restrict__ vt){
  __shared__ u16 tl[64][50];
  int t0 = blockIdx.x * 64;
  int bh = blockIdx.y; int b = bh >> 4, h = bh & 15;
  int tid = threadIdx.x;
  for (int i = tid; i < 64*48; i += 256){
    int tt = i / 48, d = i % 48;
    tl[tt][d] = qkv[(size_t)(b*T_ + t0 + tt) * N3_ + 2*C_ + h*D_ + d];
  }
  __syncthreads();
  for (int i = tid; i < 48*64; i += 256){
    int d = i >> 6, tt = i & 63;
    vt[(size_t)(bh*D_ + d) * T_ + t0 + tt] = tl[tt][d];
  }
}

// ---------------- causal flash attention, anti-diagonal pairs + LPT order ----------------
// grid: 1024 blocks; block = 256 (4 waves). Block owns q-tiles (qbA=p, qbB=31-p).
// LPT dispatch: longest pairs first within each XCD's stream; each XCD owns 8
// complete (b,h) K/V working sets. Swapped-operand MFMA, register-P, fixed-max
// softmax, 96B-pitch K, 48KB LDS (r18 verbatim).
__launch_bounds__(256)
__global__ void k_attn(const u16* __restrict__ qkv, const u16* __restrict__ vt,
                       u16* __restrict__ ao){
  __shared__ u16 lKV[2][2][6144];   // [buf][strip]: K 6144B (64 rows x 96B) + V 6144B

  const int wg = ((blockIdx.x & 7) << 7) + (blockIdx.x >> 3);   // XCD-major, 0..1023
  const int q  = wg & 127;                  // position within this XCD's stream
  const int pairI = q >> 3;                 // 0..15: longest pairs dispatched first
  const int bh = ((wg >> 7) << 3) + (q & 7);  // 8 bh per XCD (L2 locality)
  const int qbA = pairI, qbB = 31 - pairI;
  const int b = bh >> 4, h = bh & 15;
  const int tid = threadIdx.x, lane = tid & 63, w = tid >> 6;
  const int ls = lane & 15, hi = lane >> 4;
  const int krb = ls * 96 + hi * 16;     // K fragment per-lane byte base
  const f32x4 fzero = {0.f, 0.f, 0.f, 0.f};
  const bf16x8 bzero = {0, 0, 0, 0, 0, 0, 0, 0};

  // ---- Q fragments (B-operand layout; Q pre-scaled via W_attn fold) ----
  bf16x8 aqA[2], aqB[2];
  {
    const u16* qpA = qkv + (size_t)(b*T_ + qbA*64 + w*16 + ls) * N3_ + h*D_ + hi*8;
    aqA[0] = *(const bf16x8*)qpA;
    aqA[1] = (hi < 2) ? *(const bf16x8*)(qpA + 32) : bzero;
    const u16* qpB = qkv + (size_t)(b*T_ + qbB*64 + w*16 + ls) * N3_ + h*D_ + hi*8;
    aqB[0] = *(const bf16x8*)qpB;
    aqB[1] = (hi < 2) ? *(const bf16x8*)(qpB + 32) : bzero;
  }

  // ---- staging addresses ----
  const char* kg0; const char* kg1; const char* vg;
  {
    int c0 = tid,       r0 = c0 / 6, i0 = (c0 % 6) << 4;
    int c1 = tid + 256, r1 = c1 / 6, i1 = (c1 % 6) << 4;
    kg0 = (const char*)(qkv + (size_t)(b*T_ + r0) * N3_ + C_ + h*D_) + i0;
    kg1 = (const char*)(qkv + (size_t)(b*T_ + r1) * N3_ + C_ + h*D_) + i1;
    int d0  = tid >> 5;                 // 0..7
    int pb4 = (tid << 2) & 127;         // physical byte in 128B row
    int lb  = pb4 ^ (d0 << 4);          // logical byte
    int k   = lb >> 1;                  // even logical column
    int sk  = (k & 0x23) | ((k & 4) << 2) | ((k & 0x18) >> 1);  // sigma(k)
    vg = (const char*)(vt + (size_t)(bh*D_ + d0) * T_) + (sk << 1);
  }
  const size_t kstep = (size_t)64 * N3_ * 2;   // 64 K-rows per strip

  // stage ONE 64-key strip s into [buf][sl]
  auto STAGE1 = [&](int s, int buf, int sl){
    const size_t ko = (size_t)s * kstep;
    const int vo = s * 128;
    char* base = (char*)&lKV[buf][sl][0];
    __builtin_amdgcn_global_load_lds((gptr_t)(kg0 + ko), (lptr_t)(base + (tid << 4)), 16, 0, 0);
    if (tid < 128)
      __builtin_amdgcn_global_load_lds((gptr_t)(kg1 + ko), (lptr_t)(base + ((tid + 256) << 4)), 16, 0, 0);
    char* vd = base + 6144;
    #pragma unroll
    for (int it = 0; it < 6; ++it)
      __builtin_amdgcn_global_load_lds((gptr_t)(vg + vo + it * (8 * T_ * 2)),
          (lptr_t)(vd + ((tid + it*256) << 2)), 4, 0, 0);
  };

  float lsumA = 0.f, lsumB = 0.f;
  f32x4 oaccA[3], oaccB[3];
  #pragma unroll
  for (int nf = 0; nf < 3; ++nf){ oaccA[nf] = fzero; oaccB[nf] = fzero; }

  int cur = 0;

  // fixed-max softmax on S^T regs: s[nf][r] = S[key=16nf+4hi+r][q=ls].
  auto softmax = [&](f32x4 (&s)[4], float &lsum,
                     bf16x8 &pb0, bf16x8 &pb1, bool diag, int krow0, int qt){
    if (diag){
      int qg = qt + w*16 + ls;
      #pragma unroll
      for (int nf = 0; nf < 4; ++nf)
        #pragma unroll
        for (int r = 0; r < 4; ++r){
          int kg2 = krow0 + nf*16 + hi*4 + r;
          s[nf][r] = (kg2 <= qg) ? s[nf][r] : -1e30f;
        }
    }
    float p[4][4];
    #pragma unroll
    for (int nf = 0; nf < 4; ++nf)
      #pragma unroll
      for (int r = 0; r < 4; ++r){
        float e = __builtin_amdgcn_exp2f(fminf(s[nf][r], 60.f));
        p[nf][r] = e;
        lsum += e;
      }
    union { u32x4 u; bf16x8 b; } w0, w1;
    w0.u.x = cvtpk(p[0][0], p[0][1]); w0.u.y = cvtpk(p[0][2], p[0][3]);
    w0.u.z = cvtpk(p[1][0], p[1][1]); w0.u.w = cvtpk(p[1][2], p[1][3]);
    w1.u.x = cvtpk(p[2][0], p[2][1]); w1.u.y = cvtpk(p[2][2], p[2][3]);
    w1.u.z = cvtpk(p[3][0], p[3][1]); w1.u.w = cvtpk(p[3][2], p[3][3]);
    pb0 = w0.b; pb1 = w1.b;
  };

  // process one 64-key strip (global strip index ks, LDS slot sl)
  auto process = [&](int ks, int sl){
    const bool actA = (ks <= qbA);
    const u16* Kb = &lKV[cur][sl][0];
    const u16* Vb = Kb + 3072;

    f32x4 stA[4], stB[4];
    #pragma unroll
    for (int nf = 0; nf < 4; ++nf){ stA[nf] = fzero; stB[nf] = fzero; }
    #pragma unroll
    for (int kk = 0; kk < 2; ++kk){
      #pragma unroll
      for (int nf = 0; nf < 4; ++nf){
        bf16x8 bk = ld_k(Kb, krb, nf*1536 + (kk << 6));
        stB[nf] = __builtin_amdgcn_mfma_f32_16x16x32_bf16(bk, aqB[kk], stB[nf], 0, 0, 0);
        if (actA)
          stA[nf] = __builtin_amdgcn_mfma_f32_16x16x32_bf16(bk, aqA[kk], stA[nf], 0, 0, 0);
      }
    }

    bf16x8 pbA0, pbA1, pbB0, pbB1;
    if (actA) softmax(stA, lsumA, pbA0, pbA1, ks == qbA, ks*64, qbA*64);
    softmax(stB, lsumB, pbB0, pbB1, ks == qbB, ks*64, qbB*64);

    #pragma unroll
    for (int kk = 0; kk < 2; ++kk){
      int kbyte = (kk << 6) + (hi << 4);
      #pragma unroll
      for (int nf = 0; nf < 3; ++nf){
        bf16x8 bv = ld_frag(Vb, nf*16 + ls, kbyte);
        oaccB[nf] = __builtin_amdgcn_mfma_f32_16x16x32_bf16(
            bv, kk ? pbB1 : pbB0, oaccB[nf], 0, 0, 0);
        if (actA)
          oaccA[nf] = __builtin_amdgcn_mfma_f32_16x16x32_bf16(
              bv, kk ? pbA1 : pbA0, oaccA[nf], 0, 0, 0);
      }
    }
  };

  const int kb2max = qbB >> 1;
  STAGE1(0, 0, 0);
  if (qbB >= 1) STAGE1(1, 0, 1);
  __syncthreads();

  for (int kb2 = 0; kb2 <= kb2max; ++kb2){
    if (kb2 < kb2max){
      STAGE1(2*kb2 + 2, cur ^ 1, 0);
      if (2*kb2 + 3 <= qbB) STAGE1(2*kb2 + 3, cur ^ 1, 1);
    }

    process(2*kb2, 0);
    if (2*kb2 + 1 <= qbB) process(2*kb2 + 1, 1);

    if (kb2 < kb2max){
      __syncthreads();
      cur ^= 1;
    }
  }

  // ---- epilogue: finish lsum across hi-groups, normalize, store O^T ----
  float lA = lsumA; lA += __shfl_xor(lA, 16); lA += __shfl_xor(lA, 32);
  float lB = lsumB; lB += __shfl_xor(lB, 16); lB += __shfl_xor(lB, 32);
  float invA = 1.f / lA, invB = 1.f / lB;
  int tA = qbA*64 + w*16 + ls, tB = qbB*64 + w*16 + ls;
  #pragma unroll
  for (int nf = 0; nf < 3; ++nf){
    u16x4 oA, oB;
    #pragma unroll
    for (int r = 0; r < 4; ++r){
      oA[r] = f2b(oaccA[nf][r] * invA);   // O[q=ls][d = nf*16 + 4hi + r]
      oB[r] = f2b(oaccB[nf][r] * invB);
    }
    int col = h*D_ + nf*16 + hi*4;
    *(u16x4*)(ao + (size_t)(b*T_ + tA) * C_ + col) = oA;
    *(u16x4*)(ao + (size_t)(b*T_ + tB) * C_ + col) = oB;
  }
}

extern "C" void kernel_launch(void* const* d_in, const int* in_sizes, int n_in,
                              void* d_out, int out_size, void* d_ws, size_t ws_size,
                              hipStream_t stream){
  if (n_in < 4) return;
  const float* x      = (const float*)d_in[0];
  const float* W_attn = (const float*)d_in[1];
  const float* W_proj = (const float*)d_in[2];
  const float* b_proj = (const float*)d_in[3];

  char* ws = (char*)d_ws;
  size_t off = 0;
  auto alloc = [&](size_t bytes)->void*{
    void* p = ws + off; off += (bytes + 255) & ~(size_t)255; return p;
  };
  u16* xb   = (u16*)alloc((size_t)M_ * C_  * 2);
  u16* wabT = (u16*)alloc((size_t)N3_ * C_ * 2);
  u16* wpbT = (u16*)alloc((size_t)C_ * C_  * 2);
  u16* qkv  = (u16*)alloc((size_t)M_ * N3_ * 2);
  u16* vt   = (u16*)alloc((size_t)B_ * H_ * D_ * T_ * 2);
  u16* ao   = (u16*)alloc((size_t)M_ * C_  * 2);
  if (off > ws_size) return;  // workspace too small — bail cleanly

  const float scale2 = 0.20823527f;    // 48^-0.5 * log2(e), folded into W_attn Q-cols

  k_cvt<<<dim3((M_*C_/4 + 255)/256), dim3(256), 0, stream>>>(x, xb, M_*C_/4);
  k_tpose<<<dim3(N3_/32, C_/32), dim3(256), 0, stream>>>(W_attn, wabT, C_, N3_, C_, scale2);
  k_tpose<<<dim3(C_/32,  C_/32), dim3(256), 0, stream>>>(W_proj, wpbT, C_, C_, 0, 1.f);
  k_gemm<true,false><<<dim3(M_/128, N3_/128), dim3(256), 0, stream>>>(
      xb, wabT, (void*)qkv, (const float*)nullptr, N3_, C_);
  k_vt<<<dim3(T_/64, B_*H_), dim3(256), 0, stream>>>(qkv, vt);
  k_attn<<<dim3(1024), dim3(256), 0, stream>>>(qkv, vt, ao);
  k_gemm2<<<dim3(M_/64, C_/128), dim3(256), 0, stream>>>(
      ao, wpbT, (float*)d_out, b_proj, C_, C_);
}

// Round 23
// 135.998 us; speedup vs baseline: 1.0812x; 1.0066x over previous
//
#include <hip/hip_runtime.h>
#include <cstdint>
#include <cstddef>

#define B_ 4
#define T_ 2048
#define C_ 768
#define H_ 16
#define D_ 48
#define M_ (B_*T_)      // 8192
#define N3_ (3*C_)      // 2304

typedef unsigned short u16;
typedef __attribute__((ext_vector_type(8))) short bf16x8;
typedef __attribute__((ext_vector_type(4))) float f32x4;
typedef __attribute__((ext_vector_type(4))) unsigned int u32x4;
typedef __attribute__((ext_vector_type(4))) unsigned short u16x4;

typedef const __attribute__((address_space(1))) unsigned int* gptr_t;
typedef __attribute__((address_space(3))) unsigned int* lptr_t;

__device__ __forceinline__ u16 f2b(float f){
  union { float f; unsigned u; } x; x.f = f;
  unsigned u = x.u;
  return (u16)((u + 0x7FFFu + ((u >> 16) & 1u)) >> 16);
}

// v_cvt_pk_bf16_f32: packs {bf16(lo), bf16(hi)} into one u32 (RNE).
__device__ __forceinline__ unsigned cvtpk(float lo, float hi){
  unsigned r;
  asm("v_cvt_pk_bf16_f32 %0, %1, %2" : "=v"(r) : "v"(lo), "v"(hi));
  return r;
}

// Swizzled LDS fragment load (128B-pitch tiles, V + GEMM).
// Physical byte = row*128 + (col_byte ^ ((row&7)<<4)).
__device__ __forceinline__ bf16x8 ld_frag(const u16* lds, int row, int kbyte){
  const char* p = (const char*)lds + (row << 7) + (kbyte ^ ((row & 7) << 4));
  return *(const bf16x8*)p;
}

// Unswizzled 96B-pitch K fragment load: rbase = ls*96 + hi*16 (runtime),
// off = nf*1536 + kk*64 (compile-time immediate). Banks are uniformly
// distributed -> no swizzle.
__device__ __forceinline__ bf16x8 ld_k(const u16* kb, int rbase, int off){
  return *(const bf16x8*)((const char*)kb + rbase + off);
}

// ---------------- fused prologue: cvt + both weight transposes ----------------
// blocks [0,6144):        x fp32 -> bf16 (1.57M x4 chunks)
// blocks [6144,7872):     W_attn [768][2304] -> wabT [2304][768] (Q rows scaled)
// blocks [7872,8448):     W_proj [768][768]  -> wpbT [768][768]
__device__ __forceinline__ void tpose_body(const float* __restrict__ in,
                                           u16* __restrict__ out, int R, int Cn,
                                           int bx, int by, int scaleRows, float scl){
  __shared__ float tile[32][33];
  int tx = threadIdx.x & 31, ty = threadIdx.x >> 5;  // ty 0..7
  int c  = bx * 32 + tx;
  int rb = by * 32;
  #pragma unroll
  for (int r0 = 0; r0 < 32; r0 += 8)
    tile[ty + r0][tx] = in[(size_t)(rb + ty + r0) * Cn + c];
  __syncthreads();
  int oc = rb + tx;
  int cb = bx * 32;
  #pragma unroll
  for (int r0 = 0; r0 < 32; r0 += 8){
    float v = tile[tx][ty + r0];
    if (cb + ty + r0 < scaleRows) v *= scl;
    out[(size_t)(cb + ty + r0) * R + oc] = f2b(v);
  }
}

__global__ void k_prep(const float* __restrict__ x, u16* __restrict__ xb,
                       const float* __restrict__ Wa, u16* __restrict__ wabT,
                       const float* __restrict__ Wp, u16* __restrict__ wpbT,
                       float scl){
  int blk = blockIdx.x;
  if (blk < 6144){
    int i = blk * 256 + threadIdx.x;          // < 1572864 = M*C/4 exactly
    f32x4 v = *(const f32x4*)(x + 4*(size_t)i);
    u16x4 o;
    o.x = f2b(v.x); o.y = f2b(v.y); o.z = f2b(v.z); o.w = f2b(v.w);
    *(u16x4*)(xb + 4*(size_t)i) = o;
  } else if (blk < 7872){
    int id = blk - 6144;                      // 1728 = 72 x 24
    tpose_body(Wa, wabT, C_, N3_, id % 72, id / 72, C_, scl);
  } else {
    int id = blk - 7872;                      // 576 = 24 x 24
    tpose_body(Wp, wpbT, C_, C_, id % 24, id / 24, 0, 1.f);
  }
}

// ---------------- bf16 GEMM, 64x128 tile: C[m][n] = sum_k A[m][k]*Bt[n][k] ----------------
// grid (M/64, N/128). GEMM1: (128,18)=2304 blocks = 9/CU exact; GEMM2: (128,6)=768 = 3/CU.
// 4 waves side-by-side: wave w covers cols [w*32, +32), all 64 rows. 24KB LDS.
template<bool OUT_BF16, bool ADD_BIAS>
__launch_bounds__(256)
__global__ void k_gemm2(const u16* __restrict__ A, const u16* __restrict__ Bt,
                        void* __restrict__ Cout, const float* __restrict__ bias,
                        int Ndim, int Kdim){
  __shared__ u16 lA[64*64];     // 64 rows x 128B
  __shared__ u16 lB[128*64];    // 128 rows x 128B
  const int tid = threadIdx.x, lane = tid & 63, w = tid >> 6;
  const int m0 = blockIdx.x * 64, n0 = blockIdx.y * 128;
  const int wc = w * 32;
  const int ls = lane & 15, hi = lane >> 4;
  const f32x4 fzero = {0.f, 0.f, 0.f, 0.f};
  f32x4 acc[4][2];
  #pragma unroll
  for (int i = 0; i < 4; ++i){ acc[i][0] = fzero; acc[i][1] = fzero; }

  for (int k0 = 0; k0 < Kdim; k0 += 64){
    __syncthreads();
    // A: 512 chunks (2/thread)
    #pragma unroll
    for (int it = 0; it < 2; ++it){
      int c = tid + it * 256;
      int row = c >> 3, cb = (c & 7) << 4;
      int pcol = cb ^ ((row & 7) << 4);
      const char* ga = (const char*)(A + (size_t)(m0 + row) * Kdim + k0) + pcol;
      __builtin_amdgcn_global_load_lds((gptr_t)ga, (lptr_t)((char*)lA + (c << 4)), 16, 0, 0);
    }
    // B: 1024 chunks (4/thread)
    #pragma unroll
    for (int it = 0; it < 4; ++it){
      int c = tid + it * 256;
      int row = c >> 3, cb = (c & 7) << 4;
      int pcol = cb ^ ((row & 7) << 4);
      const char* gb = (const char*)(Bt + (size_t)(n0 + row) * Kdim + k0) + pcol;
      __builtin_amdgcn_global_load_lds((gptr_t)gb, (lptr_t)((char*)lB + (c << 4)), 16, 0, 0);
    }
    __syncthreads();
    #pragma unroll
    for (int kk = 0; kk < 2; ++kk){
      int kbyte = (kk << 6) + (hi << 4);
      bf16x8 af[4], bfv[2];
      #pragma unroll
      for (int i = 0; i < 4; ++i) af[i] = ld_frag(lA, i*16 + ls, kbyte);
      #pragma unroll
      for (int j = 0; j < 2; ++j) bfv[j] = ld_frag(lB, wc + j*16 + ls, kbyte);
      #pragma unroll
      for (int i = 0; i < 4; ++i)
        #pragma unroll
        for (int j = 0; j < 2; ++j)
          acc[i][j] = __builtin_amdgcn_mfma_f32_16x16x32_bf16(af[i], bfv[j], acc[i][j], 0, 0, 0);
    }
  }
  #pragma unroll
  for (int i = 0; i < 4; ++i){
    int rbase = m0 + i*16 + (hi << 2);
    #pragma unroll
    for (int j = 0; j < 2; ++j){
      int col = n0 + wc + j*16 + ls;
      float bv = ADD_BIAS ? bias[col] : 0.f;
      #pragma unroll
      for (int r = 0; r < 4; ++r){
        float v = acc[i][j][r] + bv;
        if (OUT_BF16) ((u16*)Cout)[(size_t)(rbase + r) * Ndim + col] = f2b(v);
        else          ((float*)Cout)[(size_t)(rbase + r) * Ndim + col] = v;
      }
    }
  }
}

// ---------------- V transpose: vt[bh][d][t] from qkv ----------------
__global__ void k_vt(const u16* __restrict__ qkv, u16* __restrict__ vt){
  __shared__ u16 tl[64][50];
  int t0 = blockIdx.x * 64;
  int bh = blockIdx.y; int b = bh >> 4, h = bh & 15;
  int tid = threadIdx.x;
  for (int i = tid; i < 64*48; i += 256){
    int tt = i / 48, d = i % 48;
    tl[tt][d] = qkv[(size_t)(b*T_ + t0 + tt) * N3_ + 2*C_ + h*D_ + d];
  }
  __syncthreads();
  for (int i = tid; i < 48*64; i += 256){
    int d = i >> 6, tt = i & 63;
    vt[(size_t)(bh*D_ + d) * T_ + t0 + tt] = tl[tt][d];
  }
}

// ---------------- causal flash attention, anti-diagonal pairs + LPT order ----------------
// (r18/r22 verbatim; 72.3 us, best-known)
__launch_bounds__(256)
__global__ void k_attn(const u16* __restrict__ qkv, const u16* __restrict__ vt,
                       u16* __restrict__ ao){
  __shared__ u16 lKV[2][2][6144];   // [buf][strip]: K 6144B (64 rows x 96B) + V 6144B

  const int wg = ((blockIdx.x & 7) << 7) + (blockIdx.x >> 3);   // XCD-major, 0..1023
  const int q  = wg & 127;                  // position within this XCD's stream
  const int pairI = q >> 3;                 // 0..15: longest pairs dispatched first
  const int bh = ((wg >> 7) << 3) + (q & 7);  // 8 bh per XCD (L2 locality)
  const int qbA = pairI, qbB = 31 - pairI;
  const int b = bh >> 4, h = bh & 15;
  const int tid = threadIdx.x, lane = tid & 63, w = tid >> 6;
  const int ls = lane & 15, hi = lane >> 4;
  const int krb = ls * 96 + hi * 16;     // K fragment per-lane byte base
  const f32x4 fzero = {0.f, 0.f, 0.f, 0.f};
  const bf16x8 bzero = {0, 0, 0, 0, 0, 0, 0, 0};

  // ---- Q fragments (B-operand layout; Q pre-scaled via W_attn fold) ----
  bf16x8 aqA[2], aqB[2];
  {
    const u16* qpA = qkv + (size_t)(b*T_ + qbA*64 + w*16 + ls) * N3_ + h*D_ + hi*8;
    aqA[0] = *(const bf16x8*)qpA;
    aqA[1] = (hi < 2) ? *(const bf16x8*)(qpA + 32) : bzero;
    const u16* qpB = qkv + (size_t)(b*T_ + qbB*64 + w*16 + ls) * N3_ + h*D_ + hi*8;
    aqB[0] = *(const bf16x8*)qpB;
    aqB[1] = (hi < 2) ? *(const bf16x8*)(qpB + 32) : bzero;
  }

  // ---- staging addresses ----
  const char* kg0; const char* kg1; const char* vg;
  {
    int c0 = tid,       r0 = c0 / 6, i0 = (c0 % 6) << 4;
    int c1 = tid + 256, r1 = c1 / 6, i1 = (c1 % 6) << 4;
    kg0 = (const char*)(qkv + (size_t)(b*T_ + r0) * N3_ + C_ + h*D_) + i0;
    kg1 = (const char*)(qkv + (size_t)(b*T_ + r1) * N3_ + C_ + h*D_) + i1;
    int d0  = tid >> 5;                 // 0..7
    int pb4 = (tid << 2) & 127;         // physical byte in 128B row
    int lb  = pb4 ^ (d0 << 4);          // logical byte
    int k   = lb >> 1;                  // even logical column
    int sk  = (k & 0x23) | ((k & 4) << 2) | ((k & 0x18) >> 1);  // sigma(k)
    vg = (const char*)(vt + (size_t)(bh*D_ + d0) * T_) + (sk << 1);
  }
  const size_t kstep = (size_t)64 * N3_ * 2;   // 64 K-rows per strip

  // stage ONE 64-key strip s into [buf][sl]
  auto STAGE1 = [&](int s, int buf, int sl){
    const size_t ko = (size_t)s * kstep;
    const int vo = s * 128;
    char* base = (char*)&lKV[buf][sl][0];
    __builtin_amdgcn_global_load_lds((gptr_t)(kg0 + ko), (lptr_t)(base + (tid << 4)), 16, 0, 0);
    if (tid < 128)
      __builtin_amdgcn_global_load_lds((gptr_t)(kg1 + ko), (lptr_t)(base + ((tid + 256) << 4)), 16, 0, 0);
    char* vd = base + 6144;
    #pragma unroll
    for (int it = 0; it < 6; ++it)
      __builtin_amdgcn_global_load_lds((gptr_t)(vg + vo + it * (8 * T_ * 2)),
          (lptr_t)(vd + ((tid + it*256) << 2)), 4, 0, 0);
  };

  float lsumA = 0.f, lsumB = 0.f;
  f32x4 oaccA[3], oaccB[3];
  #pragma unroll
  for (int nf = 0; nf < 3; ++nf){ oaccA[nf] = fzero; oaccB[nf] = fzero; }

  int cur = 0;

  // fixed-max softmax on S^T regs: s[nf][r] = S[key=16nf+4hi+r][q=ls].
  auto softmax = [&](f32x4 (&s)[4], float &lsum,
                     bf16x8 &pb0, bf16x8 &pb1, bool diag, int krow0, int qt){
    if (diag){
      int qg = qt + w*16 + ls;
      #pragma unroll
      for (int nf = 0; nf < 4; ++nf)
        #pragma unroll
        for (int r = 0; r < 4; ++r){
          int kg2 = krow0 + nf*16 + hi*4 + r;
          s[nf][r] = (kg2 <= qg) ? s[nf][r] : -1e30f;
        }
    }
    float p[4][4];
    #pragma unroll
    for (int nf = 0; nf < 4; ++nf)
      #pragma unroll
      for (int r = 0; r < 4; ++r){
        float e = __builtin_amdgcn_exp2f(fminf(s[nf][r], 60.f));
        p[nf][r] = e;
        lsum += e;
      }
    union { u32x4 u; bf16x8 b; } w0, w1;
    w0.u.x = cvtpk(p[0][0], p[0][1]); w0.u.y = cvtpk(p[0][2], p[0][3]);
    w0.u.z = cvtpk(p[1][0], p[1][1]); w0.u.w = cvtpk(p[1][2], p[1][3]);
    w1.u.x = cvtpk(p[2][0], p[2][1]); w1.u.y = cvtpk(p[2][2], p[2][3]);
    w1.u.z = cvtpk(p[3][0], p[3][1]); w1.u.w = cvtpk(p[3][2], p[3][3]);
    pb0 = w0.b; pb1 = w1.b;
  };

  // process one 64-key strip (global strip index ks, LDS slot sl)
  auto process = [&](int ks, int sl){
    const bool actA = (ks <= qbA);
    const u16* Kb = &lKV[cur][sl][0];
    const u16* Vb = Kb + 3072;

    f32x4 stA[4], stB[4];
    #pragma unroll
    for (int nf = 0; nf < 4; ++nf){ stA[nf] = fzero; stB[nf] = fzero; }
    #pragma unroll
    for (int kk = 0; kk < 2; ++kk){
      #pragma unroll
      for (int nf = 0; nf < 4; ++nf){
        bf16x8 bk = ld_k(Kb, krb, nf*1536 + (kk << 6));
        stB[nf] = __builtin_amdgcn_mfma_f32_16x16x32_bf16(bk, aqB[kk], stB[nf], 0, 0, 0);
        if (actA)
          stA[nf] = __builtin_amdgcn_mfma_f32_16x16x32_bf16(bk, aqA[kk], stA[nf], 0, 0, 0);
      }
    }

    bf16x8 pbA0, pbA1, pbB0, pbB1;
    if (actA) softmax(stA, lsumA, pbA0, pbA1, ks == qbA, ks*64, qbA*64);
    softmax(stB, lsumB, pbB0, pbB1, ks == qbB, ks*64, qbB*64);

    #pragma unroll
    for (int kk = 0; kk < 2; ++kk){
      int kbyte = (kk << 6) + (hi << 4);
      #pragma unroll
      for (int nf = 0; nf < 3; ++nf){
        bf16x8 bv = ld_frag(Vb, nf*16 + ls, kbyte);
        oaccB[nf] = __builtin_amdgcn_mfma_f32_16x16x32_bf16(
            bv, kk ? pbB1 : pbB0, oaccB[nf], 0, 0, 0);
        if (actA)
          oaccA[nf] = __builtin_amdgcn_mfma_f32_16x16x32_bf16(
              bv, kk ? pbA1 : pbA0, oaccA[nf], 0, 0, 0);
      }
    }
  };

  const int kb2max = qbB >> 1;
  STAGE1(0, 0, 0);
  if (qbB >= 1) STAGE1(1, 0, 1);
  __syncthreads();

  for (int kb2 = 0; kb2 <= kb2max; ++kb2){
    if (kb2 < kb2max){
      STAGE1(2*kb2 + 2, cur ^ 1, 0);
      if (2*kb2 + 3 <= qbB) STAGE1(2*kb2 + 3, cur ^ 1, 1);
    }

    process(2*kb2, 0);
    if (2*kb2 + 1 <= qbB) process(2*kb2 + 1, 1);

    if (kb2 < kb2max){
      __syncthreads();
      cur ^= 1;
    }
  }

  // ---- epilogue: finish lsum across hi-groups, normalize, store O^T ----
  float lA = lsumA; lA += __shfl_xor(lA, 16); lA += __shfl_xor(lA, 32);
  float lB = lsumB; lB += __shfl_xor(lB, 16); lB += __shfl_xor(lB, 32);
  float invA = 1.f / lA, invB = 1.f / lB;
  int tA = qbA*64 + w*16 + ls, tB = qbB*64 + w*16 + ls;
  #pragma unroll
  for (int nf = 0; nf < 3; ++nf){
    u16x4 oA, oB;
    #pragma unroll
    for (int r = 0; r < 4; ++r){
      oA[r] = f2b(oaccA[nf][r] * invA);   // O[q=ls][d = nf*16 + 4hi + r]
      oB[r] = f2b(oaccB[nf][r] * invB);
    }
    int col = h*D_ + nf*16 + hi*4;
    *(u16x4*)(ao + (size_t)(b*T_ + tA) * C_ + col) = oA;
    *(u16x4*)(ao + (size_t)(b*T_ + tB) * C_ + col) = oB;
  }
}

extern "C" void kernel_launch(void* const* d_in, const int* in_sizes, int n_in,
                              void* d_out, int out_size, void* d_ws, size_t ws_size,
                              hipStream_t stream){
  if (n_in < 4) return;
  const float* x      = (const float*)d_in[0];
  const float* W_attn = (const float*)d_in[1];
  const float* W_proj = (const float*)d_in[2];
  const float* b_proj = (const float*)d_in[3];

  char* ws = (char*)d_ws;
  size_t off = 0;
  auto alloc = [&](size_t bytes)->void*{
    void* p = ws + off; off += (bytes + 255) & ~(size_t)255; return p;
  };
  u16* xb   = (u16*)alloc((size_t)M_ * C_  * 2);
  u16* wabT = (u16*)alloc((size_t)N3_ * C_ * 2);
  u16* wpbT = (u16*)alloc((size_t)C_ * C_  * 2);
  u16* qkv  = (u16*)alloc((size_t)M_ * N3_ * 2);
  u16* vt   = (u16*)alloc((size_t)B_ * H_ * D_ * T_ * 2);
  u16* ao   = (u16*)alloc((size_t)M_ * C_  * 2);
  if (off > ws_size) return;  // workspace too small — bail cleanly

  const float scale2 = 0.20823527f;    // 48^-0.5 * log2(e), folded into W_attn Q-cols

  k_prep<<<dim3(8448), dim3(256), 0, stream>>>(x, xb, W_attn, wabT, W_proj, wpbT, scale2);
  k_gemm2<true,false><<<dim3(M_/64, N3_/128), dim3(256), 0, stream>>>(
      xb, wabT, (void*)qkv, (const float*)nullptr, N3_, C_);
  k_vt<<<dim3(T_/64, B_*H_), dim3(256), 0, stream>>>(qkv, vt);
  k_attn<<<dim3(1024), dim3(256), 0, stream>>>(qkv, vt, ao);
  k_gemm2<false,true><<<dim3(M_/64, C_/128), dim3(256), 0, stream>>>(
      ao, wpbT, d_out, b_proj, C_, C_);
}